// Round 3
// baseline (219.701 us; speedup 1.0000x reference)
//
#include <hip/hip_runtime.h>
#include <math.h>

// AttentionAggregator: out[n] = sum_k softmax_k(e_{nk}·w) * e_{nk},
// e_{nk} = embed_table[neigh_idx[n,k]].  N=100000, K=10, VOCAB=200000, D=128.
//
// R2 post-mortem: kernel is byte-transport-bound (~6 TB/s effective; 566 MB
// -> 95us). Strategy: halve gather bytes.
//   Pass 1 (dense): fp32 table -> bf16 copy in d_ws + precomputed fp32
//     scores score[v] = row_v . w.   (~154 MB streaming)
//   Pass 2 (gather): per node, scalar-load idx+scores (wave-uniform s_load,
//     scores table L2-resident), softmax in-register (no butterflies), then
//     gather only 256B bf16 rows for the weighted sum. (~310 MB)
// Accuracy: scores fp32-exact; only the weighted sum uses bf16 rows ->
// |err| <= max|bf16 quant| ~0.02, threshold 0.108.
// Fallback to the single-pass fp32 kernel if ws_size < ~52 MB.

#define KNEIGH 10
#define NPAIR  5
#define DIM    128

// ---------- Pass 1: convert + score (one wave per vocab row) ----------
__global__ __launch_bounds__(256) void convert_score_kernel(
    const float*  __restrict__ table,
    const float*  __restrict__ attn_w,
    unsigned int* __restrict__ bf_table,   // [vocab, 64] uint32 (2 bf16 each)
    float*        __restrict__ scores,     // [vocab]
    int vocab)
{
    const int gtid = blockIdx.x * blockDim.x + threadIdx.x;
    const int row  = gtid >> 6;
    if (row >= vocab) return;
    const int lane = threadIdx.x & 63;

    const float2 f = *(const float2*)(table  + (size_t)row * DIM + lane * 2);
    const float2 w = *(const float2*)(attn_w + lane * 2);

    // fp32 score via 6-level butterfly (all lanes end with the sum)
    float p = f.x * w.x + f.y * w.y;
    #pragma unroll
    for (int off = 32; off >= 1; off >>= 1)
        p += __shfl_xor(p, off, 64);

    // fp32 -> bf16 with round-to-nearest-even, pack 2 per uint32
    unsigned int bx = __float_as_uint(f.x);
    unsigned int by = __float_as_uint(f.y);
    bx = (bx + 0x7fffu + ((bx >> 16) & 1u)) >> 16;          // low half
    by = (by + 0x7fffu + ((by >> 16) & 1u)) & 0xffff0000u;  // high half
    bf_table[(size_t)row * 64 + lane] = bx | by;

    if (lane == 0) scores[row] = p;
}

// ---------- Pass 2: gather bf16 rows + weighted sum (one wave per node) ----
__global__ __launch_bounds__(256) void attn_gather_kernel(
    const unsigned int* __restrict__ bf_table,  // [vocab, 64] uint32
    const float*        __restrict__ scores,    // [vocab]
    const int*          __restrict__ idx,       // [N, K]
    float*              __restrict__ out,       // [N, D]
    int n_nodes)
{
    const int gtid = blockIdx.x * blockDim.x + threadIdx.x;
    const int node = gtid >> 6;
    if (node >= n_nodes) return;
    const int lane = threadIdx.x & 63;
    const int half = lane >> 5;    // which row of each pair
    const int sub  = lane & 31;    // dim-chunk within the row

    // wave-uniform index + score loads (compiler can use s_load; scores
    // table is 0.8 MB -> L2-resident)
    const int base = __builtin_amdgcn_readfirstlane(node) * KNEIGH;
    int id0 = idx[base + 0], id1 = idx[base + 1], id2 = idx[base + 2],
        id3 = idx[base + 3], id4 = idx[base + 4], id5 = idx[base + 5],
        id6 = idx[base + 6], id7 = idx[base + 7], id8 = idx[base + 8],
        id9 = idx[base + 9];
    float s0 = scores[id0], s1 = scores[id1], s2 = scores[id2],
          s3 = scores[id3], s4 = scores[id4], s5 = scores[id5],
          s6 = scores[id6], s7 = scores[id7], s8 = scores[id8],
          s9 = scores[id9];

    // this lane's row for each pair (ternary on VALUES -> no dynamic indexing)
    const int r0 = half ? id1 : id0;
    const int r1 = half ? id3 : id2;
    const int r2 = half ? id5 : id4;
    const int r3 = half ? id7 : id6;
    const int r4 = half ? id9 : id8;

    // issue all 5 bf16-row gathers back-to-back (each: 64 lanes x 8B = 2 rows)
    uint2 g0 = *(const uint2*)(bf_table + (size_t)r0 * 64 + sub * 2);
    uint2 g1 = *(const uint2*)(bf_table + (size_t)r1 * 64 + sub * 2);
    uint2 g2 = *(const uint2*)(bf_table + (size_t)r2 * 64 + sub * 2);
    uint2 g3 = *(const uint2*)(bf_table + (size_t)r3 * 64 + sub * 2);
    uint2 g4 = *(const uint2*)(bf_table + (size_t)r4 * 64 + sub * 2);

    // softmax over K=10 (in registers, redundant per lane)
    float m = fmaxf(fmaxf(fmaxf(fmaxf(s0, s1), fmaxf(s2, s3)),
                          fmaxf(fmaxf(s4, s5), fmaxf(s6, s7))),
                    fmaxf(s8, s9));
    s0 = __expf(s0 - m); s1 = __expf(s1 - m); s2 = __expf(s2 - m);
    s3 = __expf(s3 - m); s4 = __expf(s4 - m); s5 = __expf(s5 - m);
    s6 = __expf(s6 - m); s7 = __expf(s7 - m); s8 = __expf(s8 - m);
    s9 = __expf(s9 - m);
    const float inv = 1.0f /
        (s0 + s1 + s2 + s3 + s4 + s5 + s6 + s7 + s8 + s9);
    const float w0 = (half ? s1 : s0) * inv;
    const float w1 = (half ? s3 : s2) * inv;
    const float w2 = (half ? s5 : s4) * inv;
    const float w3 = (half ? s7 : s6) * inv;
    const float w4 = (half ? s9 : s8) * inv;

    // weighted sum; unpack bf16 pairs (lo -> <<16, hi -> mask)
    float4 acc = make_float4(0.f, 0.f, 0.f, 0.f);
    #define ACCUM(G, WK)                                                   \
        {                                                                  \
            const float e0 = __uint_as_float((G).x << 16);                 \
            const float e1 = __uint_as_float((G).x & 0xffff0000u);         \
            const float e2 = __uint_as_float((G).y << 16);                 \
            const float e3 = __uint_as_float((G).y & 0xffff0000u);         \
            acc.x = fmaf((WK), e0, acc.x);                                 \
            acc.y = fmaf((WK), e1, acc.y);                                 \
            acc.z = fmaf((WK), e2, acc.z);                                 \
            acc.w = fmaf((WK), e3, acc.w);                                 \
        }
    ACCUM(g0, w0) ACCUM(g1, w1) ACCUM(g2, w2) ACCUM(g3, w3) ACCUM(g4, w4)
    #undef ACCUM

    // combine even-row half with odd-row half; lower half stores
    acc.x += __shfl_xor(acc.x, 32, 64);
    acc.y += __shfl_xor(acc.y, 32, 64);
    acc.z += __shfl_xor(acc.z, 32, 64);
    acc.w += __shfl_xor(acc.w, 32, 64);

    if (half == 0)
        *(float4*)(out + (size_t)node * DIM + sub * 4) = acc;
}

// ---------- Fallback: single-pass fp32 (R1 kernel) ----------
__global__ __launch_bounds__(256) void attn_agg_fp32_kernel(
    const float* __restrict__ table,
    const float* __restrict__ attn_w,
    const int*   __restrict__ idx,
    float*       __restrict__ out,
    int n_nodes)
{
    const int gtid = blockIdx.x * blockDim.x + threadIdx.x;
    const int node = gtid >> 6;
    const int lane = threadIdx.x & 63;
    if (node >= n_nodes) return;

    const float2 wv = *(const float2*)(attn_w + lane * 2);
    int my_idx = 0;
    if (lane < KNEIGH) my_idx = idx[node * KNEIGH + lane];

    float2 f[KNEIGH];
    float  s[KNEIGH];
    #pragma unroll
    for (int k = 0; k < KNEIGH; ++k) {
        const int id = __shfl(my_idx, k, 64);
        f[k] = *(const float2*)(table + (size_t)id * DIM + lane * 2);
        float p = f[k].x * wv.x + f[k].y * wv.y;
        #pragma unroll
        for (int off = 32; off >= 1; off >>= 1)
            p += __shfl_xor(p, off, 64);
        s[k] = p;
    }
    float m = s[0];
    #pragma unroll
    for (int k = 1; k < KNEIGH; ++k) m = fmaxf(m, s[k]);
    float denom = 0.f;
    #pragma unroll
    for (int k = 0; k < KNEIGH; ++k) { s[k] = __expf(s[k] - m); denom += s[k]; }
    const float inv = 1.0f / denom;
    float2 acc = make_float2(0.f, 0.f);
    #pragma unroll
    for (int k = 0; k < KNEIGH; ++k) {
        const float wk = s[k] * inv;
        acc.x = fmaf(wk, f[k].x, acc.x);
        acc.y = fmaf(wk, f[k].y, acc.y);
    }
    *(float2*)(out + (size_t)node * DIM + lane * 2) = acc;
}

extern "C" void kernel_launch(void* const* d_in, const int* in_sizes, int n_in,
                              void* d_out, int out_size, void* d_ws, size_t ws_size,
                              hipStream_t stream) {
    const float* table  = (const float*)d_in[0];   // [VOCAB, D] fp32
    const float* attn_w = (const float*)d_in[1];   // [D] fp32
    const int*   idx    = (const int*)d_in[2];     // [N, K] int32
    float*       out    = (float*)d_out;           // [N, D] fp32

    const int vocab   = in_sizes[0] / DIM;
    const int n_nodes = in_sizes[2] / KNEIGH;

    const size_t bf_bytes = (size_t)vocab * (DIM / 2) * sizeof(unsigned int);
    const size_t need     = bf_bytes + (size_t)vocab * sizeof(float);

    if (ws_size >= need) {
        unsigned int* bf_table = (unsigned int*)d_ws;
        float*        scores   = (float*)((char*)d_ws + bf_bytes);

        const int blocks1 = (vocab + 3) / 4;        // 4 waves/block
        convert_score_kernel<<<blocks1, 256, 0, stream>>>(
            table, attn_w, bf_table, scores, vocab);

        const int blocks2 = (n_nodes + 3) / 4;
        attn_gather_kernel<<<blocks2, 256, 0, stream>>>(
            bf_table, scores, idx, out, n_nodes);
    } else {
        const int blocks = (n_nodes + 3) / 4;
        attn_agg_fp32_kernel<<<blocks, 256, 0, stream>>>(
            table, attn_w, idx, out, n_nodes);
    }
}

// Round 5
// 208.251 us; speedup vs baseline: 1.0550x; 1.0550x over previous
//
#include <hip/hip_runtime.h>
#include <math.h>

// AttentionAggregator: out[n] = sum_k softmax_k(e_{nk}·w) * e_{nk},
// e_{nk} = embed_table[neigh_idx[n,k]].  N=100000, K=10, VOCAB=200000, D=128.
//
// Two-pass byte-reduction (R3) with issue-efficiency fixes (R4/R5):
//   Pass 1 (convert): fp32 table -> bf16 copy + fp32 scores. 2 rows/wave
//     (32 lanes x float4), 5-level butterfly per half. ~154 MB.
//   Pass 2 (gather): 2 nodes/wave, 16-lane quarters; each uint4 wave-load
//     fetches FOUR 256B bf16 rows (2 nodes = 20 rows = 5 loads). Scores are
//     wave-uniform scalar loads from the 0.8 MB fp32 score table (L2-hot);
//     softmax in-register. ~310 MB.
// Accuracy: scores fp32-exact; only the weighted sum uses bf16 rows
// (absmax ~0.03, threshold 0.108). All accumulators are explicit scalars
// (R2 lesson: no LDS demotion). R5: removed __builtin_nontemporal_load
// (rejects HIP vector types on gfx950).

#define KNEIGH 10
#define DIM    128

// ---------- Pass 1: convert + score (one wave per TWO vocab rows) ----------
__global__ __launch_bounds__(256) void convert_score_kernel(
    const float*  __restrict__ table,
    const float*  __restrict__ attn_w,
    unsigned int* __restrict__ bf_table,   // [vocab, 64] uint32 (2 bf16 each)
    float*        __restrict__ scores,     // [vocab]
    int vocab)
{
    const int gtid = blockIdx.x * blockDim.x + threadIdx.x;
    const int lane = threadIdx.x & 63;
    const int half = lane >> 5;
    const int sub  = lane & 31;
    const int row  = (gtid >> 6) * 2 + half;
    if (row >= vocab) return;              // no barriers below -> safe

    const float4 f  = *(const float4*)(table + (size_t)row * DIM + sub * 4);
    const float4 w4 = *(const float4*)(attn_w + sub * 4);

    // fp32 score: 5-level butterfly within each 32-lane half
    float p = f.x * w4.x + f.y * w4.y + f.z * w4.z + f.w * w4.w;
    #pragma unroll
    for (int off = 16; off >= 1; off >>= 1)
        p += __shfl_xor(p, off, 64);

    // fp32 -> bf16 RNE, pack 2 per word (low word = even dim)
    unsigned int ux = __float_as_uint(f.x), uy = __float_as_uint(f.y);
    unsigned int uz = __float_as_uint(f.z), uw = __float_as_uint(f.w);
    ux = (ux + 0x7fffu + ((ux >> 16) & 1u)) >> 16;
    uy = (uy + 0x7fffu + ((uy >> 16) & 1u)) & 0xffff0000u;
    uz = (uz + 0x7fffu + ((uz >> 16) & 1u)) >> 16;
    uw = (uw + 0x7fffu + ((uw >> 16) & 1u)) & 0xffff0000u;
    uint2 packed = make_uint2(ux | uy, uz | uw);
    *(uint2*)(bf_table + (size_t)row * 64 + sub * 2) = packed;

    if (sub == 0) scores[row] = p;
}

// ---------- Pass 2: gather (one wave per TWO nodes, 4 rows per load) -------
__global__ __launch_bounds__(256) void attn_gather_kernel(
    const unsigned int* __restrict__ bf_table,  // [vocab, 64] uint32
    const float*        __restrict__ scores,    // [vocab]
    const int*          __restrict__ idx,       // [N, K]
    float*              __restrict__ out,       // [N, D]
    int n_nodes)
{
    const int gtid = blockIdx.x * blockDim.x + threadIdx.x;
    const int wid  = gtid >> 6;
    const int n0   = wid * 2;
    if (n0 >= n_nodes) return;
    const int  n1   = n0 + 1;
    const bool has1 = (n1 < n_nodes);
    const int  lane = threadIdx.x & 63;
    const int  q    = lane >> 4;            // quarter: which row of each load
    const int  sub  = lane & 15;            // 16B dim-chunk within the row

    const int b0 = __builtin_amdgcn_readfirstlane(n0) * KNEIGH;
    const int b1 = has1 ? b0 + KNEIGH : b0;

    // 20 wave-uniform index loads (s_load) + 20 score loads (L2-hot 0.8 MB)
    const int ia0 = idx[b0+0], ia1 = idx[b0+1], ia2 = idx[b0+2], ia3 = idx[b0+3],
              ia4 = idx[b0+4], ia5 = idx[b0+5], ia6 = idx[b0+6], ia7 = idx[b0+7],
              ia8 = idx[b0+8], ia9 = idx[b0+9];
    const int ib0 = idx[b1+0], ib1 = idx[b1+1], ib2 = idx[b1+2], ib3 = idx[b1+3],
              ib4 = idx[b1+4], ib5 = idx[b1+5], ib6 = idx[b1+6], ib7 = idx[b1+7],
              ib8 = idx[b1+8], ib9 = idx[b1+9];

    // this lane's row for each of the 5 loads (rows 4j+q, 2-node order)
    const int r0 = (q == 0) ? ia0 : (q == 1) ? ia1 : (q == 2) ? ia2 : ia3;
    const int r1 = (q == 0) ? ia4 : (q == 1) ? ia5 : (q == 2) ? ia6 : ia7;
    const int r2 = (q == 0) ? ia8 : (q == 1) ? ia9 : (q == 2) ? ib0 : ib1;
    const int r3 = (q == 0) ? ib2 : (q == 1) ? ib3 : (q == 2) ? ib4 : ib5;
    const int r4 = (q == 0) ? ib6 : (q == 1) ? ib7 : (q == 2) ? ib8 : ib9;

    // 5 gathers, each = 4 full bf16 rows (16 lanes x 16B x 4 quarters)
    const uint4 g0 = *(const uint4*)(bf_table + (size_t)r0 * 64 + sub * 4);
    const uint4 g1 = *(const uint4*)(bf_table + (size_t)r1 * 64 + sub * 4);
    const uint4 g2 = *(const uint4*)(bf_table + (size_t)r2 * 64 + sub * 4);
    const uint4 g3 = *(const uint4*)(bf_table + (size_t)r3 * 64 + sub * 4);
    const uint4 g4 = *(const uint4*)(bf_table + (size_t)r4 * 64 + sub * 4);

    float sa0 = scores[ia0], sa1 = scores[ia1], sa2 = scores[ia2],
          sa3 = scores[ia3], sa4 = scores[ia4], sa5 = scores[ia5],
          sa6 = scores[ia6], sa7 = scores[ia7], sa8 = scores[ia8],
          sa9 = scores[ia9];
    float sb0 = scores[ib0], sb1 = scores[ib1], sb2 = scores[ib2],
          sb3 = scores[ib3], sb4 = scores[ib4], sb5 = scores[ib5],
          sb6 = scores[ib6], sb7 = scores[ib7], sb8 = scores[ib8],
          sb9 = scores[ib9];

    // softmax per node (redundant per lane)
    float ma = fmaxf(fmaxf(fmaxf(fmaxf(sa0, sa1), fmaxf(sa2, sa3)),
                           fmaxf(fmaxf(sa4, sa5), fmaxf(sa6, sa7))),
                     fmaxf(sa8, sa9));
    sa0 = __expf(sa0 - ma); sa1 = __expf(sa1 - ma); sa2 = __expf(sa2 - ma);
    sa3 = __expf(sa3 - ma); sa4 = __expf(sa4 - ma); sa5 = __expf(sa5 - ma);
    sa6 = __expf(sa6 - ma); sa7 = __expf(sa7 - ma); sa8 = __expf(sa8 - ma);
    sa9 = __expf(sa9 - ma);
    const float inva = 1.0f /
        (sa0 + sa1 + sa2 + sa3 + sa4 + sa5 + sa6 + sa7 + sa8 + sa9);

    float mb = fmaxf(fmaxf(fmaxf(fmaxf(sb0, sb1), fmaxf(sb2, sb3)),
                           fmaxf(fmaxf(sb4, sb5), fmaxf(sb6, sb7))),
                     fmaxf(sb8, sb9));
    sb0 = __expf(sb0 - mb); sb1 = __expf(sb1 - mb); sb2 = __expf(sb2 - mb);
    sb3 = __expf(sb3 - mb); sb4 = __expf(sb4 - mb); sb5 = __expf(sb5 - mb);
    sb6 = __expf(sb6 - mb); sb7 = __expf(sb7 - mb); sb8 = __expf(sb8 - mb);
    sb9 = __expf(sb9 - mb);
    const float invb = 1.0f /
        (sb0 + sb1 + sb2 + sb3 + sb4 + sb5 + sb6 + sb7 + sb8 + sb9);

    // this lane's weight for each load (row 4j+q)
    const float w0 = ((q == 0) ? sa0 : (q == 1) ? sa1 : (q == 2) ? sa2 : sa3) * inva;
    const float w1 = ((q == 0) ? sa4 : (q == 1) ? sa5 : (q == 2) ? sa6 : sa7) * inva;
    const float w2 = (q == 0) ? sa8 * inva : (q == 1) ? sa9 * inva
                   : (q == 2) ? sb0 * invb : sb1 * invb;
    const float w3 = ((q == 0) ? sb2 : (q == 1) ? sb3 : (q == 2) ? sb4 : sb5) * invb;
    const float w4 = ((q == 0) ? sb6 : (q == 1) ? sb7 : (q == 2) ? sb8 : sb9) * invb;

    // accumulate 8 dims/lane into node0 (a*) and node1 (b*) accumulators
    float a0=0.f,a1=0.f,a2=0.f,a3=0.f,a4=0.f,a5=0.f,a6=0.f,a7=0.f;
    float b0f=0.f,b1f=0.f,b2f=0.f,b3f=0.f,b4f=0.f,b5f=0.f,b6f=0.f,b7f=0.f;

    #define UNPK(G, W, A0,A1,A2,A3,A4,A5,A6,A7)                                \
        A0 = fmaf((W), __uint_as_float((G).x << 16),          A0);             \
        A1 = fmaf((W), __uint_as_float((G).x & 0xffff0000u),  A1);             \
        A2 = fmaf((W), __uint_as_float((G).y << 16),          A2);             \
        A3 = fmaf((W), __uint_as_float((G).y & 0xffff0000u),  A3);             \
        A4 = fmaf((W), __uint_as_float((G).z << 16),          A4);             \
        A5 = fmaf((W), __uint_as_float((G).z & 0xffff0000u),  A5);             \
        A6 = fmaf((W), __uint_as_float((G).w << 16),          A6);             \
        A7 = fmaf((W), __uint_as_float((G).w & 0xffff0000u),  A7);

    UNPK(g0, w0, a0,a1,a2,a3,a4,a5,a6,a7)
    UNPK(g1, w1, a0,a1,a2,a3,a4,a5,a6,a7)
    // load 2 is mixed: quarters 0,1 -> node0; quarters 2,3 -> node1
    {
        float c0=0.f,c1=0.f,c2=0.f,c3=0.f,c4=0.f,c5=0.f,c6=0.f,c7=0.f;
        UNPK(g2, w2, c0,c1,c2,c3,c4,c5,c6,c7)
        const bool lo = (q < 2);
        a0 += lo ? c0 : 0.f; a1 += lo ? c1 : 0.f; a2 += lo ? c2 : 0.f;
        a3 += lo ? c3 : 0.f; a4 += lo ? c4 : 0.f; a5 += lo ? c5 : 0.f;
        a6 += lo ? c6 : 0.f; a7 += lo ? c7 : 0.f;
        b0f += lo ? 0.f : c0; b1f += lo ? 0.f : c1; b2f += lo ? 0.f : c2;
        b3f += lo ? 0.f : c3; b4f += lo ? 0.f : c4; b5f += lo ? 0.f : c5;
        b6f += lo ? 0.f : c6; b7f += lo ? 0.f : c7;
    }
    UNPK(g3, w3, b0f,b1f,b2f,b3f,b4f,b5f,b6f,b7f)
    UNPK(g4, w4, b0f,b1f,b2f,b3f,b4f,b5f,b6f,b7f)
    #undef UNPK

    // combine the 4 quarters (xor16 merges q0/q1 and q2/q3; xor32 the rest)
    #define RED(X) X += __shfl_xor(X, 16, 64); X += __shfl_xor(X, 32, 64);
    RED(a0) RED(a1) RED(a2) RED(a3) RED(a4) RED(a5) RED(a6) RED(a7)
    RED(b0f) RED(b1f) RED(b2f) RED(b3f) RED(b4f) RED(b5f) RED(b6f) RED(b7f)
    #undef RED

    if (q == 0) {
        float* p = out + (size_t)n0 * DIM + sub * 8;
        *(float4*)(p)     = make_float4(a0, a1, a2, a3);
        *(float4*)(p + 4) = make_float4(a4, a5, a6, a7);
    } else if (q == 1 && has1) {
        float* p = out + (size_t)n1 * DIM + sub * 8;
        *(float4*)(p)     = make_float4(b0f, b1f, b2f, b3f);
        *(float4*)(p + 4) = make_float4(b4f, b5f, b6f, b7f);
    }
}

// ---------- Fallback: single-pass fp32 (R1 kernel) ----------
__global__ __launch_bounds__(256) void attn_agg_fp32_kernel(
    const float* __restrict__ table,
    const float* __restrict__ attn_w,
    const int*   __restrict__ idx,
    float*       __restrict__ out,
    int n_nodes)
{
    const int gtid = blockIdx.x * blockDim.x + threadIdx.x;
    const int node = gtid >> 6;
    const int lane = threadIdx.x & 63;
    if (node >= n_nodes) return;

    const float2 wv = *(const float2*)(attn_w + lane * 2);
    int my_idx = 0;
    if (lane < KNEIGH) my_idx = idx[node * KNEIGH + lane];

    float2 f[KNEIGH];
    float  s[KNEIGH];
    #pragma unroll
    for (int k = 0; k < KNEIGH; ++k) {
        const int id = __shfl(my_idx, k, 64);
        f[k] = *(const float2*)(table + (size_t)id * DIM + lane * 2);
        float p = f[k].x * wv.x + f[k].y * wv.y;
        #pragma unroll
        for (int off = 32; off >= 1; off >>= 1)
            p += __shfl_xor(p, off, 64);
        s[k] = p;
    }
    float m = s[0];
    #pragma unroll
    for (int k = 1; k < KNEIGH; ++k) m = fmaxf(m, s[k]);
    float denom = 0.f;
    #pragma unroll
    for (int k = 0; k < KNEIGH; ++k) { s[k] = __expf(s[k] - m); denom += s[k]; }
    const float inv = 1.0f / denom;
    float2 acc = make_float2(0.f, 0.f);
    #pragma unroll
    for (int k = 0; k < KNEIGH; ++k) {
        const float wk = s[k] * inv;
        acc.x = fmaf(wk, f[k].x, acc.x);
        acc.y = fmaf(wk, f[k].y, acc.y);
    }
    *(float2*)(out + (size_t)node * DIM + lane * 2) = acc;
}

extern "C" void kernel_launch(void* const* d_in, const int* in_sizes, int n_in,
                              void* d_out, int out_size, void* d_ws, size_t ws_size,
                              hipStream_t stream) {
    const float* table  = (const float*)d_in[0];   // [VOCAB, D] fp32
    const float* attn_w = (const float*)d_in[1];   // [D] fp32
    const int*   idx    = (const int*)d_in[2];     // [N, K] int32
    float*       out    = (float*)d_out;           // [N, D] fp32

    const int vocab   = in_sizes[0] / DIM;
    const int n_nodes = in_sizes[2] / KNEIGH;

    const size_t bf_bytes = (size_t)vocab * (DIM / 2) * sizeof(unsigned int);
    const size_t need     = bf_bytes + (size_t)vocab * sizeof(float);

    if (ws_size >= need) {
        unsigned int* bf_table = (unsigned int*)d_ws;
        float*        scores   = (float*)((char*)d_ws + bf_bytes);

        const int waves1  = (vocab + 1) / 2;       // 2 rows per wave
        const int blocks1 = (waves1 + 3) / 4;      // 4 waves per block
        convert_score_kernel<<<blocks1, 256, 0, stream>>>(
            table, attn_w, bf_table, scores, vocab);

        const int waves2  = (n_nodes + 1) / 2;     // 2 nodes per wave
        const int blocks2 = (waves2 + 3) / 4;
        attn_gather_kernel<<<blocks2, 256, 0, stream>>>(
            bf_table, scores, idx, out, n_nodes);
    } else {
        const int blocks = (n_nodes + 3) / 4;
        attn_agg_fp32_kernel<<<blocks, 256, 0, stream>>>(
            table, attn_w, idx, out, n_nodes);
    }
}

// Round 6
// 198.073 us; speedup vs baseline: 1.1092x; 1.0514x over previous
//
#include <hip/hip_runtime.h>
#include <math.h>

// AttentionAggregator: out[n] = sum_k softmax_k(e_{nk}·w) * e_{nk},
// e_{nk} = embed_table[neigh_idx[n,k]].  N=100000, K=10, VOCAB=200000, D=128.
//
// R6: two-pass with INT8 per-row-scale table (gather bytes halved vs bf16).
//   Pass 1 (convert): fp32 table -> per-row-max-scaled biased-uint8 rows
//     (128 B/row) + aux float2 {score(fp32-exact), scale}. ~130 MB.
//   Pass 2 (gather): 2 nodes/wave, 16-lane quarters; each uint2 wave-load
//     fetches FOUR 128B int8 rows. Dequant folds scale into the per-row
//     weight and the -128 bias into a per-node scalar constant. ~185 MB.
// Error: scores fp32-exact; int8 quant err <= rowmax/253 ~ 0.02 per elem,
// output err <= max_k err (weights sum to 1) -> ~0.02-0.05, threshold 0.108.
// All accumulators explicit scalars (R2 lesson: no LDS demotion).

#define KNEIGH 10
#define DIM    128
#define QMAX   126.5f

// ---------- Pass 1: convert + score + scale (one wave per TWO rows) --------
__global__ __launch_bounds__(256) void convert_q8_kernel(
    const float*  __restrict__ table,
    const float*  __restrict__ attn_w,
    unsigned int* __restrict__ q8,      // [vocab][32] dwords (4 x uint8 each)
    float2*       __restrict__ aux,     // [vocab] {score, scale}
    int vocab)
{
    const int gtid = blockIdx.x * blockDim.x + threadIdx.x;
    const int lane = threadIdx.x & 63;
    const int half = lane >> 5;
    const int sub  = lane & 31;
    const int row  = (gtid >> 6) * 2 + half;
    if (row >= vocab) return;              // no barriers below -> safe

    const float4 f  = *(const float4*)(table + (size_t)row * DIM + sub * 4);
    const float4 w4 = *(const float4*)(attn_w + sub * 4);

    // fp32 score + row absmax: two 5-level butterflies within each 32-half
    float p = f.x * w4.x + f.y * w4.y + f.z * w4.z + f.w * w4.w;
    float am = fmaxf(fmaxf(fabsf(f.x), fabsf(f.y)),
                     fmaxf(fabsf(f.z), fabsf(f.w)));
    #pragma unroll
    for (int off = 16; off >= 1; off >>= 1) {
        p  += __shfl_xor(p, off, 64);
        am  = fmaxf(am, __shfl_xor(am, off, 64));
    }

    const float scale = am * (1.0f / QMAX);
    const float inv   = (am > 0.f) ? (QMAX / am) : 0.f;

    // biased-uint8 encode: q = rint(x*inv) + 128 in [1,255], no clamp needed
    const int q0 = (int)rintf(f.x * inv) + 128;
    const int q1 = (int)rintf(f.y * inv) + 128;
    const int q2 = (int)rintf(f.z * inv) + 128;
    const int q3 = (int)rintf(f.w * inv) + 128;
    q8[(size_t)row * 32 + sub] =
        (unsigned)q0 | ((unsigned)q1 << 8) | ((unsigned)q2 << 16) |
        ((unsigned)q3 << 24);

    if (sub == 0) aux[row] = make_float2(p, scale);
}

// ---------- Pass 2: gather (one wave per TWO nodes, 4 rows per load) -------
__global__ __launch_bounds__(256) void attn_gather_q8_kernel(
    const unsigned int* __restrict__ q8,    // [vocab][32] dwords
    const float2*       __restrict__ aux,   // [vocab] {score, scale}
    const int*          __restrict__ idx,   // [N, K]
    float*              __restrict__ out,   // [N, D]
    int n_nodes)
{
    const int gtid = blockIdx.x * blockDim.x + threadIdx.x;
    const int wid  = gtid >> 6;
    const int n0   = wid * 2;
    if (n0 >= n_nodes) return;
    const int  n1   = n0 + 1;
    const bool has1 = (n1 < n_nodes);
    const int  lane = threadIdx.x & 63;
    const int  q    = lane >> 4;            // quarter: which row of each load
    const int  sub  = lane & 15;            // 8B dim-chunk within the row

    const int b0 = __builtin_amdgcn_readfirstlane(n0) * KNEIGH;
    const int b1 = has1 ? b0 + KNEIGH : b0;

    // wave-uniform index loads (s_load) + aux loads (L2-hot 1.6 MB)
    const int ia0 = idx[b0+0], ia1 = idx[b0+1], ia2 = idx[b0+2], ia3 = idx[b0+3],
              ia4 = idx[b0+4], ia5 = idx[b0+5], ia6 = idx[b0+6], ia7 = idx[b0+7],
              ia8 = idx[b0+8], ia9 = idx[b0+9];
    const int ib0 = idx[b1+0], ib1 = idx[b1+1], ib2 = idx[b1+2], ib3 = idx[b1+3],
              ib4 = idx[b1+4], ib5 = idx[b1+5], ib6 = idx[b1+6], ib7 = idx[b1+7],
              ib8 = idx[b1+8], ib9 = idx[b1+9];

    // this lane's row for each of the 5 loads (rows 4j+q, 2-node order)
    const int r0 = (q == 0) ? ia0 : (q == 1) ? ia1 : (q == 2) ? ia2 : ia3;
    const int r1 = (q == 0) ? ia4 : (q == 1) ? ia5 : (q == 2) ? ia6 : ia7;
    const int r2 = (q == 0) ? ia8 : (q == 1) ? ia9 : (q == 2) ? ib0 : ib1;
    const int r3 = (q == 0) ? ib2 : (q == 1) ? ib3 : (q == 2) ? ib4 : ib5;
    const int r4 = (q == 0) ? ib6 : (q == 1) ? ib7 : (q == 2) ? ib8 : ib9;

    // 5 gathers, each = 4 full 128B int8 rows (16 lanes x 8B x 4 quarters)
    const uint2 g0 = *(const uint2*)(q8 + (size_t)r0 * 32 + sub * 2);
    const uint2 g1 = *(const uint2*)(q8 + (size_t)r1 * 32 + sub * 2);
    const uint2 g2 = *(const uint2*)(q8 + (size_t)r2 * 32 + sub * 2);
    const uint2 g3 = *(const uint2*)(q8 + (size_t)r3 * 32 + sub * 2);
    const uint2 g4 = *(const uint2*)(q8 + (size_t)r4 * 32 + sub * 2);

    const float2 aa0 = aux[ia0], aa1 = aux[ia1], aa2 = aux[ia2],
                 aa3 = aux[ia3], aa4 = aux[ia4], aa5 = aux[ia5],
                 aa6 = aux[ia6], aa7 = aux[ia7], aa8 = aux[ia8],
                 aa9 = aux[ia9];
    const float2 ab0 = aux[ib0], ab1 = aux[ib1], ab2 = aux[ib2],
                 ab3 = aux[ib3], ab4 = aux[ib4], ab5 = aux[ib5],
                 ab6 = aux[ib6], ab7 = aux[ib7], ab8 = aux[ib8],
                 ab9 = aux[ib9];

    // softmax per node (redundant per lane) from fp32-exact scores
    float sa0 = aa0.x, sa1 = aa1.x, sa2 = aa2.x, sa3 = aa3.x, sa4 = aa4.x,
          sa5 = aa5.x, sa6 = aa6.x, sa7 = aa7.x, sa8 = aa8.x, sa9 = aa9.x;
    float ma = fmaxf(fmaxf(fmaxf(fmaxf(sa0, sa1), fmaxf(sa2, sa3)),
                           fmaxf(fmaxf(sa4, sa5), fmaxf(sa6, sa7))),
                     fmaxf(sa8, sa9));
    sa0 = __expf(sa0 - ma); sa1 = __expf(sa1 - ma); sa2 = __expf(sa2 - ma);
    sa3 = __expf(sa3 - ma); sa4 = __expf(sa4 - ma); sa5 = __expf(sa5 - ma);
    sa6 = __expf(sa6 - ma); sa7 = __expf(sa7 - ma); sa8 = __expf(sa8 - ma);
    sa9 = __expf(sa9 - ma);
    const float inva = 1.0f /
        (sa0 + sa1 + sa2 + sa3 + sa4 + sa5 + sa6 + sa7 + sa8 + sa9);

    float sb0 = ab0.x, sb1 = ab1.x, sb2 = ab2.x, sb3 = ab3.x, sb4 = ab4.x,
          sb5 = ab5.x, sb6 = ab6.x, sb7 = ab7.x, sb8 = ab8.x, sb9 = ab9.x;
    float mb = fmaxf(fmaxf(fmaxf(fmaxf(sb0, sb1), fmaxf(sb2, sb3)),
                           fmaxf(fmaxf(sb4, sb5), fmaxf(sb6, sb7))),
                     fmaxf(sb8, sb9));
    sb0 = __expf(sb0 - mb); sb1 = __expf(sb1 - mb); sb2 = __expf(sb2 - mb);
    sb3 = __expf(sb3 - mb); sb4 = __expf(sb4 - mb); sb5 = __expf(sb5 - mb);
    sb6 = __expf(sb6 - mb); sb7 = __expf(sb7 - mb); sb8 = __expf(sb8 - mb);
    sb9 = __expf(sb9 - mb);
    const float invb = 1.0f /
        (sb0 + sb1 + sb2 + sb3 + sb4 + sb5 + sb6 + sb7 + sb8 + sb9);

    // per-row effective weight = softmax_weight * row_scale
    const float ta0 = sa0 * inva * aa0.y, ta1 = sa1 * inva * aa1.y,
                ta2 = sa2 * inva * aa2.y, ta3 = sa3 * inva * aa3.y,
                ta4 = sa4 * inva * aa4.y, ta5 = sa5 * inva * aa5.y,
                ta6 = sa6 * inva * aa6.y, ta7 = sa7 * inva * aa7.y,
                ta8 = sa8 * inva * aa8.y, ta9 = sa9 * inva * aa9.y;
    const float tb0 = sb0 * invb * ab0.y, tb1 = sb1 * invb * ab1.y,
                tb2 = sb2 * invb * ab2.y, tb3 = sb3 * invb * ab3.y,
                tb4 = sb4 * invb * ab4.y, tb5 = sb5 * invb * ab5.y,
                tb6 = sb6 * invb * ab6.y, tb7 = sb7 * invb * ab7.y,
                tb8 = sb8 * invb * ab8.y, tb9 = sb9 * invb * ab9.y;

    // per-node bias correction: sum_k w_k*s_k*(q-128) -> subtract 128*sum(t)
    const float Ca = -128.f * (ta0 + ta1 + ta2 + ta3 + ta4 +
                               ta5 + ta6 + ta7 + ta8 + ta9);
    const float Cb = -128.f * (tb0 + tb1 + tb2 + tb3 + tb4 +
                               tb5 + tb6 + tb7 + tb8 + tb9);

    // this lane's weight for each load (row 4j+q)
    const float w0 = (q == 0) ? ta0 : (q == 1) ? ta1 : (q == 2) ? ta2 : ta3;
    const float w1 = (q == 0) ? ta4 : (q == 1) ? ta5 : (q == 2) ? ta6 : ta7;
    const float w2 = (q == 0) ? ta8 : (q == 1) ? ta9 : (q == 2) ? tb0 : tb1;
    const float w3 = (q == 0) ? tb2 : (q == 1) ? tb3 : (q == 2) ? tb4 : tb5;
    const float w4 = (q == 0) ? tb6 : (q == 1) ? tb7 : (q == 2) ? tb8 : tb9;

    // accumulate 8 dims/lane into node0 (a*) and node1 (b*) accumulators
    float a0=0.f,a1=0.f,a2=0.f,a3=0.f,a4=0.f,a5=0.f,a6=0.f,a7=0.f;
    float b0f=0.f,b1f=0.f,b2f=0.f,b3f=0.f,b4f=0.f,b5f=0.f,b6f=0.f,b7f=0.f;

    // byte b of dword d = dim sub*8 + d*4 + b (matches convert packing)
    #define UNPK(G, W, A0,A1,A2,A3,A4,A5,A6,A7)                                \
        A0 = fmaf((W), (float)((G).x & 0xffu),         A0);                    \
        A1 = fmaf((W), (float)(((G).x >> 8) & 0xffu),  A1);                    \
        A2 = fmaf((W), (float)(((G).x >> 16) & 0xffu), A2);                    \
        A3 = fmaf((W), (float)((G).x >> 24),           A3);                    \
        A4 = fmaf((W), (float)((G).y & 0xffu),         A4);                    \
        A5 = fmaf((W), (float)(((G).y >> 8) & 0xffu),  A5);                    \
        A6 = fmaf((W), (float)(((G).y >> 16) & 0xffu), A6);                    \
        A7 = fmaf((W), (float)((G).y >> 24),           A7);

    UNPK(g0, w0, a0,a1,a2,a3,a4,a5,a6,a7)
    UNPK(g1, w1, a0,a1,a2,a3,a4,a5,a6,a7)
    // load 2 is mixed: quarters 0,1 -> node0; quarters 2,3 -> node1
    {
        float c0=0.f,c1=0.f,c2=0.f,c3=0.f,c4=0.f,c5=0.f,c6=0.f,c7=0.f;
        UNPK(g2, w2, c0,c1,c2,c3,c4,c5,c6,c7)
        const bool lo = (q < 2);
        a0 += lo ? c0 : 0.f; a1 += lo ? c1 : 0.f; a2 += lo ? c2 : 0.f;
        a3 += lo ? c3 : 0.f; a4 += lo ? c4 : 0.f; a5 += lo ? c5 : 0.f;
        a6 += lo ? c6 : 0.f; a7 += lo ? c7 : 0.f;
        b0f += lo ? 0.f : c0; b1f += lo ? 0.f : c1; b2f += lo ? 0.f : c2;
        b3f += lo ? 0.f : c3; b4f += lo ? 0.f : c4; b5f += lo ? 0.f : c5;
        b6f += lo ? 0.f : c6; b7f += lo ? 0.f : c7;
    }
    UNPK(g3, w3, b0f,b1f,b2f,b3f,b4f,b5f,b6f,b7f)
    UNPK(g4, w4, b0f,b1f,b2f,b3f,b4f,b5f,b6f,b7f)
    #undef UNPK

    // combine the 4 quarters (xor16 merges q0/q1 and q2/q3; xor32 the rest)
    #define RED(X) X += __shfl_xor(X, 16, 64); X += __shfl_xor(X, 32, 64);
    RED(a0) RED(a1) RED(a2) RED(a3) RED(a4) RED(a5) RED(a6) RED(a7)
    RED(b0f) RED(b1f) RED(b2f) RED(b3f) RED(b4f) RED(b5f) RED(b6f) RED(b7f)
    #undef RED

    if (q == 0) {
        float* p = out + (size_t)n0 * DIM + sub * 8;
        *(float4*)(p)     = make_float4(a0 + Ca, a1 + Ca, a2 + Ca, a3 + Ca);
        *(float4*)(p + 4) = make_float4(a4 + Ca, a5 + Ca, a6 + Ca, a7 + Ca);
    } else if (q == 1 && has1) {
        float* p = out + (size_t)n1 * DIM + sub * 8;
        *(float4*)(p)     = make_float4(b0f + Cb, b1f + Cb, b2f + Cb, b3f + Cb);
        *(float4*)(p + 4) = make_float4(b4f + Cb, b5f + Cb, b6f + Cb, b7f + Cb);
    }
}

// ---------- Fallback: single-pass fp32 (R1 kernel) ----------
__global__ __launch_bounds__(256) void attn_agg_fp32_kernel(
    const float* __restrict__ table,
    const float* __restrict__ attn_w,
    const int*   __restrict__ idx,
    float*       __restrict__ out,
    int n_nodes)
{
    const int gtid = blockIdx.x * blockDim.x + threadIdx.x;
    const int node = gtid >> 6;
    const int lane = threadIdx.x & 63;
    if (node >= n_nodes) return;

    const float2 wv = *(const float2*)(attn_w + lane * 2);
    int my_idx = 0;
    if (lane < KNEIGH) my_idx = idx[node * KNEIGH + lane];

    float2 f[KNEIGH];
    float  s[KNEIGH];
    #pragma unroll
    for (int k = 0; k < KNEIGH; ++k) {
        const int id = __shfl(my_idx, k, 64);
        f[k] = *(const float2*)(table + (size_t)id * DIM + lane * 2);
        float p = f[k].x * wv.x + f[k].y * wv.y;
        #pragma unroll
        for (int off = 32; off >= 1; off >>= 1)
            p += __shfl_xor(p, off, 64);
        s[k] = p;
    }
    float m = s[0];
    #pragma unroll
    for (int k = 1; k < KNEIGH; ++k) m = fmaxf(m, s[k]);
    float denom = 0.f;
    #pragma unroll
    for (int k = 0; k < KNEIGH; ++k) { s[k] = __expf(s[k] - m); denom += s[k]; }
    const float inv = 1.0f / denom;
    float2 acc = make_float2(0.f, 0.f);
    #pragma unroll
    for (int k = 0; k < KNEIGH; ++k) {
        const float wk = s[k] * inv;
        acc.x = fmaf(wk, f[k].x, acc.x);
        acc.y = fmaf(wk, f[k].y, acc.y);
    }
    *(float2*)(out + (size_t)node * DIM + lane * 2) = acc;
}

extern "C" void kernel_launch(void* const* d_in, const int* in_sizes, int n_in,
                              void* d_out, int out_size, void* d_ws, size_t ws_size,
                              hipStream_t stream) {
    const float* table  = (const float*)d_in[0];   // [VOCAB, D] fp32
    const float* attn_w = (const float*)d_in[1];   // [D] fp32
    const int*   idx    = (const int*)d_in[2];     // [N, K] int32
    float*       out    = (float*)d_out;           // [N, D] fp32

    const int vocab   = in_sizes[0] / DIM;
    const int n_nodes = in_sizes[2] / KNEIGH;

    const size_t q8_bytes = (size_t)vocab * DIM;             // 25.6 MB
    const size_t need     = q8_bytes + (size_t)vocab * sizeof(float2);

    if (ws_size >= need) {
        unsigned int* q8  = (unsigned int*)d_ws;
        float2*       aux = (float2*)((char*)d_ws + q8_bytes);

        const int waves1  = (vocab + 1) / 2;       // 2 rows per wave
        const int blocks1 = (waves1 + 3) / 4;      // 4 waves per block
        convert_q8_kernel<<<blocks1, 256, 0, stream>>>(
            table, attn_w, q8, aux, vocab);

        const int waves2  = (n_nodes + 1) / 2;     // 2 nodes per wave
        const int blocks2 = (waves2 + 3) / 4;
        attn_gather_q8_kernel<<<blocks2, 256, 0, stream>>>(
            q8, aux, idx, out, n_nodes);
    } else {
        const int blocks = (n_nodes + 3) / 4;
        attn_agg_fp32_kernel<<<blocks, 256, 0, stream>>>(
            table, attn_w, idx, out, n_nodes);
    }
}